// Round 3
// baseline (386.717 us; speedup 1.0000x reference)
//
#include <hip/hip_runtime.h>

// Fully-fused 3-axis inverse DWT (DB4, periodization) on (4,256,256,256) fp32.
// Per block: output tile T=(16 d1, 16 d2, 32 d3); staged input X=(22,22,38)
// (11/11 s|w rows per strided axis, 19/19 for d3). All three transforms run
// in ONE LDS buffer using the "dead-slot" in-place trick:
//   slot p (s half) is last read at pair p -> write y[2p] there;
//   slot 11+p (w half) likewise -> y[2p+1]. Later phases index via
//   phys(r) = r&1 ? 11+(r>>1) : r>>1  (compile-time under unroll).
// Polyphase filters: a[j]=h[6-2j], b[j]=h[7-2j], c[j]=h[2j+1], d[j]=-h[2j].

#define FILT_DECL(h)                                          \
  const float a0 = h[6], a1 = h[4], a2 = h[2], a3 = h[0];     \
  const float b0 = h[7], b1 = h[5], b2 = h[3], b3 = h[1];     \
  const float c0 = h[1], c1 = h[3], c2 = h[5], c3 = h[7];     \
  const float d0 = -h[0], d1 = -h[2], d2 = -h[4], d3 = -h[6];

#define Y0(s0,s1,s2,s3,w0,w1,w2,w3)                                        \
  fmaf(w3, c3, fmaf(w2, c2, fmaf(w1, c1, fmaf(w0, c0,                      \
  fmaf(s3, a3, fmaf(s2, a2, fmaf(s1, a1, s0 * a0)))))))
#define Y1(s0,s1,s2,s3,w0,w1,w2,w3)                                        \
  fmaf(w3, d3, fmaf(w2, d2, fmaf(w1, d1, fmaf(w0, d0,                      \
  fmaf(s3, b3, fmaf(s2, b2, fmaf(s1, b1, s0 * b0)))))))

__global__ __launch_bounds__(512, 4) void wav_fused(const float* __restrict__ in,
                                                    float* __restrict__ out,
                                                    const float* __restrict__ hg) {
  __shared__ float buf[22 * 22 * 38];            // 18392 floats = 73.6 KB
  const int t = threadIdx.x;
  const int d3t = blockIdx.x;                    // 0..7   (32 outputs each)
  const int d2t = blockIdx.y;                    // 0..15  (16 outputs each)
  const int d1t = blockIdx.z & 15;               // 0..15
  const int b   = blockIdx.z >> 4;               // 0..3

  FILT_DECL(hg)

  const int mb1 = 8 * d1t - 3;
  const int mb2 = 8 * d2t - 3;
  const int mb3 = 16 * d3t - 3;

  // staging plane (i2,i3): 22*38 = 836 elements; thread covers e=t and e=512+t
  const int i2a = t / 38, i3a = t % 38;
  const int e2  = 512 + t;                       // second chunk, valid t<324
  const int i2b = e2 / 38, i3b = e2 % 38;

  auto gmap2 = [&](int i2) { return (i2 < 11) ? ((mb2 + i2) & 127)
                                              : (128 + ((mb2 + i2 - 11) & 127)); };
  auto gmap3 = [&](int i3) { return (i3 < 19) ? ((mb3 + i3) & 127)
                                              : (128 + ((mb3 + i3 - 19) & 127)); };
  const int offA = gmap2(i2a) * 256 + gmap3(i3a);
  const int offB = gmap2(i2b) * 256 + gmap3(i3b);

  const float* __restrict__ inb = in + (size_t)b * 16777216;

  // ---------- stage: global -> LDS ----------
  for (int i1 = 0; i1 < 22; ++i1) {
    const int g1 = (i1 < 11) ? ((mb1 + i1) & 127)
                             : (128 + ((mb1 + i1 - 11) & 127));
    const float* __restrict__ src = inb + (size_t)g1 * 65536;
    buf[i1 * 836 + t] = src[offA];
    if (t < 324) buf[i1 * 836 + 512 + t] = src[offB];
  }
  __syncthreads();

  // ---------- phase 2: axis-1 transform, in-place per (i2,i3) column ----------
  auto axis1_col = [&](int col) {
    float S[11], W[11];
#pragma unroll
    for (int i = 0; i < 11; ++i) S[i] = buf[i * 836 + col];
#pragma unroll
    for (int i = 0; i < 11; ++i) W[i] = buf[(11 + i) * 836 + col];
#pragma unroll
    for (int p = 0; p < 8; ++p) {
      const float y0 = Y0(S[p], S[p+1], S[p+2], S[p+3], W[p], W[p+1], W[p+2], W[p+3]);
      const float y1 = Y1(S[p], S[p+1], S[p+2], S[p+3], W[p], W[p+1], W[p+2], W[p+3]);
      buf[p * 836 + col] = y0;          // out-row 2p   -> phys slot p
      buf[(11 + p) * 836 + col] = y1;   // out-row 2p+1 -> phys slot 11+p
    }
  };
  axis1_col(t);
  if (t < 324) axis1_col(512 + t);
  __syncthreads();

  auto phys = [](int r) { return (r & 1) ? (11 + (r >> 1)) : (r >> 1); };

  // ---------- phase 3: axis-2 transform, in-place per (r,i3) column ----------
  auto axis2_col = [&](int r, int i3) {
    const int base = phys(r) * 836 + i3;
    float S[11], W[11];
#pragma unroll
    for (int i = 0; i < 11; ++i) S[i] = buf[base + i * 38];
#pragma unroll
    for (int i = 0; i < 11; ++i) W[i] = buf[base + (11 + i) * 38];
#pragma unroll
    for (int p = 0; p < 8; ++p) {
      const float y0 = Y0(S[p], S[p+1], S[p+2], S[p+3], W[p], W[p+1], W[p+2], W[p+3]);
      const float y1 = Y1(S[p], S[p+1], S[p+2], S[p+3], W[p], W[p+1], W[p+2], W[p+3]);
      buf[base + p * 38] = y0;
      buf[base + (11 + p) * 38] = y1;
    }
  };
  // 16 x 38 = 608 columns; reuse (i2a,i3a)/(i2b,i3b) decompositions (same /38)
  axis2_col(i2a, i3a);                   // t < 512 -> r=i2a<14 valid
  if (t < 96) axis2_col(i2b, i3b);       // covers q = 512..607
  __syncthreads();

  // ---------- phase 4: axis-3 transform + global store ----------
  const int row = t >> 1, h4 = t & 1;    // 256 (r,c) rows x 2 d-halves
  const int r4 = row >> 4, c4 = row & 15;
  const int base4 = phys(r4) * 836 + phys(c4) * 38;
  const int p0 = 8 * h4;                 // pairs p0..p0+7 -> d = 16*h4..16*h4+15
  float S[11], W[11];
#pragma unroll
  for (int i = 0; i < 11; ++i) S[i] = buf[base4 + p0 + i];
#pragma unroll
  for (int i = 0; i < 11; ++i) W[i] = buf[base4 + 19 + p0 + i];
  float y[16];
#pragma unroll
  for (int p = 0; p < 8; ++p) {
    y[2*p]   = Y0(S[p], S[p+1], S[p+2], S[p+3], W[p], W[p+1], W[p+2], W[p+3]);
    y[2*p+1] = Y1(S[p], S[p+1], S[p+2], S[p+3], W[p], W[p+1], W[p+2], W[p+3]);
  }
  float* __restrict__ dst = out
      + ((((size_t)b * 256 + 16 * d1t + r4) * 256 + 16 * d2t + c4) * 256)
      + 32 * d3t + 16 * h4;
#pragma unroll
  for (int v = 0; v < 4; ++v)
    *reinterpret_cast<float4*>(dst + 4 * v) =
        make_float4(y[4*v], y[4*v+1], y[4*v+2], y[4*v+3]);
}

extern "C" void kernel_launch(void* const* d_in, const int* in_sizes, int n_in,
                              void* d_out, int out_size, void* d_ws, size_t ws_size,
                              hipStream_t stream) {
  const float* x = (const float*)d_in[0];
  const float* h = (const float*)d_in[1];
  float* out = (float*)d_out;
  // grid: d3 tiles (8) x d2 tiles (16) x (d1 tiles (16) * batch (4))
  wav_fused<<<dim3(8, 16, 64), 512, 0, stream>>>(x, out, h);
}

// Round 4
// 300.187 us; speedup vs baseline: 1.2883x; 1.2883x over previous
//
#include <hip/hip_runtime.h>

// Inverse 3D DWT (DB4, periodization), (4,256,256,256) fp32.
// T1 (axis1) and T23 (axes 2,3) commute -> 2 passes:
//   pass 1: axis-1 streaming transform, x -> ws (float4-vectorized)
//   pass 2: fused axis-2 + axis-3 per (b,d1) slice, ws -> out
// Polyphase: y[2m]   = sum_j s[(m+j-3)&127]*a[j] + w[..]*c[j]
//            y[2m+1] = sum_j s[(m+j-3)&127]*b[j] + w[..]*d[j]
// a[j]=h[6-2j], b[j]=h[7-2j], c[j]=h[2j+1], d[j]=-h[2j].
// NOTE: FILT_DECL owns identifiers a0..a3,b0..b3,c0..c3,d0..d3.

#define FILT_DECL(h)                                          \
  const float a0 = h[6], a1 = h[4], a2 = h[2], a3 = h[0];     \
  const float b0 = h[7], b1 = h[5], b2 = h[3], b3 = h[1];     \
  const float c0 = h[1], c1 = h[3], c2 = h[5], c3 = h[7];     \
  const float d0 = -h[0], d1 = -h[2], d2 = -h[4], d3 = -h[6];

#define Y0(s0,s1,s2,s3,w0,w1,w2,w3)                                        \
  fmaf(w3, c3, fmaf(w2, c2, fmaf(w1, c1, fmaf(w0, c0,                      \
  fmaf(s3, a3, fmaf(s2, a2, fmaf(s1, a1, s0 * a0)))))))
#define Y1(s0,s1,s2,s3,w0,w1,w2,w3)                                        \
  fmaf(w3, d3, fmaf(w2, d2, fmaf(w1, d1, fmaf(w0, d0,                      \
  fmaf(s3, b3, fmaf(s2, b2, fmaf(s1, b1, s0 * b0)))))))

// ---------------- pass 1: axis 1 (row stride 65536), float4, in -> tmp ----
__global__ __launch_bounds__(256) void wav_axis1_v4(const float4* __restrict__ in,
                                                    float4* __restrict__ tmp,
                                                    const float* __restrict__ h) {
  const int inner = blockIdx.x * 256 + threadIdx.x;          // 0..16383 (float4)
  const int m0 = blockIdx.y * 64;
  const size_t base = (size_t)blockIdx.z * (256u * 16384u) + (unsigned)inner;
  const float4* __restrict__ ps = in + base;                 // s rows 0..127
  const float4* __restrict__ pw = in + base + (size_t)128 * 16384;
  float4* __restrict__ po = tmp + base;
  FILT_DECL(h)
  float4 s0 = ps[(size_t)((m0 - 3) & 127) * 16384];
  float4 s1 = ps[(size_t)((m0 - 2) & 127) * 16384];
  float4 s2 = ps[(size_t)((m0 - 1) & 127) * 16384];
  float4 w0 = pw[(size_t)((m0 - 3) & 127) * 16384];
  float4 w1 = pw[(size_t)((m0 - 2) & 127) * 16384];
  float4 w2 = pw[(size_t)((m0 - 1) & 127) * 16384];
  for (int m = m0; m < m0 + 64; ++m) {
    const float4 s3 = ps[(size_t)m * 16384];
    const float4 w3 = pw[(size_t)m * 16384];
    float4 y0, y1;
    y0.x = Y0(s0.x, s1.x, s2.x, s3.x, w0.x, w1.x, w2.x, w3.x);
    y0.y = Y0(s0.y, s1.y, s2.y, s3.y, w0.y, w1.y, w2.y, w3.y);
    y0.z = Y0(s0.z, s1.z, s2.z, s3.z, w0.z, w1.z, w2.z, w3.z);
    y0.w = Y0(s0.w, s1.w, s2.w, s3.w, w0.w, w1.w, w2.w, w3.w);
    y1.x = Y1(s0.x, s1.x, s2.x, s3.x, w0.x, w1.x, w2.x, w3.x);
    y1.y = Y1(s0.y, s1.y, s2.y, s3.y, w0.y, w1.y, w2.y, w3.y);
    y1.z = Y1(s0.z, s1.z, s2.z, s3.z, w0.z, w1.z, w2.z, w3.z);
    y1.w = Y1(s0.w, s1.w, s2.w, s3.w, w0.w, w1.w, w2.w, w3.w);
    po[(size_t)(2 * m) * 16384] = y0;
    po[(size_t)(2 * m + 1) * 16384] = y1;
    s0 = s1; s1 = s2; s2 = s3;
    w0 = w1; w1 = w2; w2 = w3;
  }
}

// ---------------- pass 2: fused axes 2+3 per (b,d1) slice, tmp -> out -----
// Output tile 32 (d2) x 128 (d3); staged footprint 38 x 134 wrapped, 20.8 KB.
// axis-2: one thread per column (dead-slot in-place, thread-exclusive).
// axis-3: 32 rows x 8 pair-chunks = 256 threads, float4 stores to global.
__global__ __launch_bounds__(256, 4) void wav_t23(const float* __restrict__ tmp,
                                                  float* __restrict__ out,
                                                  const float* __restrict__ hg) {
  __shared__ float lb[38 * 137];                 // stride 137 (odd) vs banks
  const int t = threadIdx.x;
  const int d2t = blockIdx.x & 7;                // 8 tiles of 32 rows
  const int d3t = blockIdx.x >> 3;               // 2 tiles of 128 cols
  const size_t slice = blockIdx.y;               // b*256 + d1
  const float* __restrict__ src = tmp + slice * 65536;
  FILT_DECL(hg)
  const int mb2 = 16 * d2t - 3;
  const int mb3 = 64 * d3t - 3;

  // stage (38 i2) x (134 i3): s|w halves wrapped per axis
  for (int e = t; e < 38 * 134; e += 256) {
    const int i2 = e / 134, i3 = e - i2 * 134;
    const int g2 = (i2 < 19) ? ((mb2 + i2) & 127) : (128 + ((mb2 + i2 - 19) & 127));
    const int g3 = (i3 < 67) ? ((mb3 + i3) & 127) : (128 + ((mb3 + i3 - 67) & 127));
    lb[i2 * 137 + i3] = src[g2 * 256 + g3];
  }
  __syncthreads();

  // axis-2 down columns (rows 0..18 = s, 19..37 = w); dead-slot in place:
  // pair p: y[2p] -> row p, y[2p+1] -> row 19+p (row p dead after pair p).
  if (t < 134) {
    float S[19], W[19];
#pragma unroll
    for (int i = 0; i < 19; ++i) S[i] = lb[i * 137 + t];
#pragma unroll
    for (int i = 0; i < 19; ++i) W[i] = lb[(19 + i) * 137 + t];
#pragma unroll
    for (int p = 0; p < 16; ++p) {
      lb[p * 137 + t]        = Y0(S[p], S[p+1], S[p+2], S[p+3], W[p], W[p+1], W[p+2], W[p+3]);
      lb[(19 + p) * 137 + t] = Y1(S[p], S[p+1], S[p+2], S[p+3], W[p], W[p+1], W[p+2], W[p+3]);
    }
  }
  __syncthreads();

  // axis-3 along rows; local out row r -> phys row (r&1 ? 19+(r>>1) : r>>1)
  const int r = t >> 3, pc = t & 7;
  const int prow = ((r & 1) ? (19 + (r >> 1)) : (r >> 1)) * 137;
  const int cc0 = 8 * pc;                        // pairs 8*pc .. 8*pc+7
  float S[11], W[11];
#pragma unroll
  for (int i = 0; i < 11; ++i) S[i] = lb[prow + cc0 + i];
#pragma unroll
  for (int i = 0; i < 11; ++i) W[i] = lb[prow + 67 + cc0 + i];
  float y[16];
#pragma unroll
  for (int q = 0; q < 8; ++q) {
    y[2*q]   = Y0(S[q], S[q+1], S[q+2], S[q+3], W[q], W[q+1], W[q+2], W[q+3]);
    y[2*q+1] = Y1(S[q], S[q+1], S[q+2], S[q+3], W[q], W[q+1], W[q+2], W[q+3]);
  }
  float* __restrict__ dst = out + slice * 65536
      + (size_t)(32 * d2t + r) * 256 + 128 * d3t + 16 * pc;
#pragma unroll
  for (int v = 0; v < 4; ++v)
    *reinterpret_cast<float4*>(dst + 4 * v) =
        make_float4(y[4*v], y[4*v+1], y[4*v+2], y[4*v+3]);
}

// ================= fallback 3-pass (verified round 2) =================
__global__ __launch_bounds__(256) void wav_axis1(const float* __restrict__ in,
                                                 float* __restrict__ out,
                                                 const float* __restrict__ h) {
  const int inner = blockIdx.x * 256 + threadIdx.x;
  const int m0 = blockIdx.y * 64;
  const size_t base = (size_t)blockIdx.z * (256u * 65536u) + (unsigned)inner;
  const float* __restrict__ ps = in + base;
  const float* __restrict__ pw = in + base + (size_t)128 * 65536;
  float* __restrict__ po = out + base;
  FILT_DECL(h)
  float s0 = ps[(size_t)((m0 - 3) & 127) * 65536];
  float s1 = ps[(size_t)((m0 - 2) & 127) * 65536];
  float s2 = ps[(size_t)((m0 - 1) & 127) * 65536];
  float w0 = pw[(size_t)((m0 - 3) & 127) * 65536];
  float w1 = pw[(size_t)((m0 - 2) & 127) * 65536];
  float w2 = pw[(size_t)((m0 - 1) & 127) * 65536];
  for (int m = m0; m < m0 + 64; ++m) {
    const float s3 = ps[(size_t)m * 65536];
    const float w3 = pw[(size_t)m * 65536];
    po[(size_t)(2 * m) * 65536] = Y0(s0, s1, s2, s3, w0, w1, w2, w3);
    po[(size_t)(2 * m + 1) * 65536] = Y1(s0, s1, s2, s3, w0, w1, w2, w3);
    s0 = s1; s1 = s2; s2 = s3;
    w0 = w1; w1 = w2; w2 = w3;
  }
}

__global__ __launch_bounds__(256) void wav_axis2(float* __restrict__ buf,
                                                 const float* __restrict__ h) {
  __shared__ float tile[256][32];
  const int t = threadIdx.x;
  const int c = t & 31;
  const int g = t >> 5;
  const size_t slice = (size_t)(blockIdx.x >> 3);
  const int col0 = (blockIdx.x & 7) * 32;
  float* __restrict__ p = buf + slice * 65536 + col0;
#pragma unroll
  for (int i = 0; i < 32; ++i) {
    const int rr = i * 8 + g;
    tile[rr][c] = p[rr * 256 + c];
  }
  __syncthreads();
  FILT_DECL(h)
  const int m0 = g * 16;
  float s0 = tile[(m0 - 3) & 127][c];
  float s1 = tile[(m0 - 2) & 127][c];
  float s2 = tile[(m0 - 1) & 127][c];
  float w0 = tile[128 + ((m0 - 3) & 127)][c];
  float w1 = tile[128 + ((m0 - 2) & 127)][c];
  float w2 = tile[128 + ((m0 - 1) & 127)][c];
#pragma unroll
  for (int m = m0; m < m0 + 16; ++m) {
    const float s3 = tile[m][c];
    const float w3 = tile[128 + m][c];
    p[(2 * m) * 256 + c] = Y0(s0, s1, s2, s3, w0, w1, w2, w3);
    p[(2 * m + 1) * 256 + c] = Y1(s0, s1, s2, s3, w0, w1, w2, w3);
    s0 = s1; s1 = s2; s2 = s3;
    w0 = w1; w1 = w2; w2 = w3;
  }
}

__global__ __launch_bounds__(256) void wav_axis3(float* __restrict__ buf,
                                                 const float* __restrict__ h) {
  __shared__ float tile[512];
  const int t = threadIdx.x;
  float* __restrict__ p = buf + (size_t)blockIdx.x * 512;
  tile[t] = p[t];
  tile[256 + t] = p[256 + t];
  __syncthreads();
  FILT_DECL(h)
  const int rr = t >> 7;
  const int m = t & 127;
  const float* __restrict__ line = tile + rr * 256;
  const float s0 = line[(m - 3) & 127];
  const float s1 = line[(m - 2) & 127];
  const float s2 = line[(m - 1) & 127];
  const float s3 = line[m];
  const float w0 = line[128 + ((m - 3) & 127)];
  const float w1 = line[128 + ((m - 2) & 127)];
  const float w2 = line[128 + ((m - 1) & 127)];
  const float w3 = line[128 + m];
  float2 y;
  y.x = Y0(s0, s1, s2, s3, w0, w1, w2, w3);
  y.y = Y1(s0, s1, s2, s3, w0, w1, w2, w3);
  *reinterpret_cast<float2*>(p + rr * 256 + 2 * m) = y;
}

extern "C" void kernel_launch(void* const* d_in, const int* in_sizes, int n_in,
                              void* d_out, int out_size, void* d_ws, size_t ws_size,
                              hipStream_t stream) {
  const float* x = (const float*)d_in[0];
  const float* h = (const float*)d_in[1];
  float* out = (float*)d_out;
  const size_t need = (size_t)4 * 256 * 256 * 256 * 4;   // 268 MB intermediate

  if (ws_size >= need) {
    float* tmp = (float*)d_ws;
    wav_axis1_v4<<<dim3(64, 2, 4), 256, 0, stream>>>(
        (const float4*)x, (float4*)tmp, h);
    wav_t23<<<dim3(16, 1024), 256, 0, stream>>>(tmp, out, h);
  } else {
    wav_axis1<<<dim3(256, 2, 4), 256, 0, stream>>>(x, out, h);
    wav_axis2<<<dim3(8192), 256, 0, stream>>>(out, h);
    wav_axis3<<<dim3(131072), 256, 0, stream>>>(out, h);
  }
}